// Round 17
// baseline (146.812 us; speedup 1.0000x reference)
//
#include <hip/hip_runtime.h>

#define EMB 64

#if defined(__has_builtin)
#if __has_builtin(__builtin_amdgcn_sdot4)
#define USE_SDOT 1
#endif
#endif
#ifndef USE_SDOT
#define USE_SDOT 0
#endif

typedef float f32x4 __attribute__((ext_vector_type(4)));

// ---------- Kernel A: segment boundaries (segment_ids sorted) ----------
__global__ void seg_bounds_kernel(const int* __restrict__ seg,
                                  int* __restrict__ row_start,
                                  int T, int B) {
    int t = blockIdx.x * blockDim.x + threadIdx.x;
    if (t >= T) return;
    int s  = seg[t];
    int sp = (t == 0) ? -1 : seg[t - 1];
    for (int b = sp + 1; b <= s; ++b) row_start[b] = t;
    if (t == T - 1) {
        for (int b = s + 1; b <= B; ++b) row_start[b] = T;
    }
}

// ---------- Kernel Q: f32 -> signed int4 stored excess-8 ----------
// value = s * q',  q' in [-7,7],  stored nibble b = q' + 8.
__global__ __launch_bounds__(256) void cvt_q4_kernel(
    const float* __restrict__ src, uint* __restrict__ dst,
    float* __restrict__ scales, int nrows) {
    const int wave = (int)((blockIdx.x * blockDim.x + threadIdx.x) >> 6);
    const int lane = threadIdx.x & 63;
    const int g = lane >> 3, sub = lane & 7;
    const int r = wave * 8 + g;
    if (r >= nrows) return;

    const float* p = src + (size_t)r * EMB + (sub << 3);
    float e[8];
    #pragma unroll
    for (int k = 0; k < 8; ++k) e[k] = p[k];
    float mx = 0.f;
    #pragma unroll
    for (int k = 0; k < 8; ++k) mx = fmaxf(mx, fabsf(e[k]));
    mx = fmaxf(mx, __shfl_xor(mx, 1, 64));
    mx = fmaxf(mx, __shfl_xor(mx, 2, 64));
    mx = fmaxf(mx, __shfl_xor(mx, 4, 64));

    const float scale = mx * (1.0f / 7.0f);
    const float inv   = (mx > 0.f) ? (7.0f / mx) : 0.f;

    uint w = 0;
    #pragma unroll
    for (int k = 0; k < 8; ++k) {
        int q = (int)rintf(e[k] * inv);
        q = q < -7 ? -7 : (q > 7 ? 7 : q);
        w |= ((uint)(q + 8)) << (4 * k);
    }
    dst[(size_t)r * 8 + sub] = w;
    if (sub == 0) scales[r] = scale;
}

// ---------- Kernel B v12: 2 lanes/row, uint4 gathers (min addresses) ------
// Wave = 32 pairs x 2 lanes. Pair owns row wave*32+pair; lane half=lane&1
// covers dims [32*half .. 32*half+31] = 4 q4 dwords = ONE uint4 load.
// Addresses per entry: q4 2, scale 2, flat ~1 (vs 17 in the 8x8 layout).
// Dot via 8 sdot4 per lane-entry; pair-reduce = 1 shfl_xor.
__global__ __launch_bounds__(256) void svdpp_main_q4(
    const int*   __restrict__ scientist_ids,
    const int*   __restrict__ paper_ids,
    const int*   __restrict__ flat_papers,
    const int*   __restrict__ row_start,
    const float* __restrict__ scientist_factors,
    const float* __restrict__ paper_factors,
    const uint*  __restrict__ imp_q4,
    const float* __restrict__ imp_scale,
    const float* __restrict__ scientist_bias,
    const float* __restrict__ paper_bias,
    float*       __restrict__ out,
    int B) {
    const int wave = (int)((blockIdx.x * blockDim.x + threadIdx.x) >> 6);
    const int lane = threadIdx.x & 63;
    const int pair = lane >> 1;        // 0..31 -> row
    const int half = lane & 1;         // dims [32*half, 32*half+31]
    const int b    = wave * 32 + pair;
    if (b >= B) return;

    const int sid   = __builtin_nontemporal_load(scientist_ids + b);
    const int pid   = __builtin_nontemporal_load(paper_ids + b);
    const int start = row_start[b];
    const int end   = row_start[b + 1];

    // pe: this lane's 32 dims (8 float4, hot cached table)
    const float4* pf = reinterpret_cast<const float4*>(
        paper_factors + ((size_t)pid << 6)) + half * 8;
    float4 pe[8];
    #pragma unroll
    for (int k = 0; k < 8; ++k) pe[k] = pf[k];

    // se base dot (zero-reuse table, nt vector loads)
    const f32x4* sf = reinterpret_cast<const f32x4*>(
        scientist_factors + ((size_t)sid << 6) + half * 32);
    float base = 0.f;
    #pragma unroll
    for (int k = 0; k < 8; ++k) {
        const f32x4 s = __builtin_nontemporal_load(sf + k);
        base += s.x * pe[k].x + s.y * pe[k].y + s.z * pe[k].z + s.w * pe[k].w;
    }

    const float sb = __builtin_nontemporal_load(scientist_bias + sid);
    const float pb = __builtin_nontemporal_load(paper_bias + pid);

#if USE_SDOT
    // quantize this lane's 32 pe dims to int8
    float pmax = 0.f;
    #pragma unroll
    for (int k = 0; k < 8; ++k) {
        pmax = fmaxf(pmax, fmaxf(fmaxf(fabsf(pe[k].x), fabsf(pe[k].y)),
                                 fmaxf(fabsf(pe[k].z), fabsf(pe[k].w))));
    }
    const float sp   = pmax * (1.0f / 127.0f);
    const float pinv = (pmax > 0.f) ? (127.0f / pmax) : 0.f;
    // dword jj (dims 8jj..8jj+7 of this lane) -> pe[2jj], pe[2jj+1]
    int plo[4], phi[4];
    int psum = 0;
    #pragma unroll
    for (int jj = 0; jj < 4; ++jj) {
        const float4 a = pe[2 * jj], c = pe[2 * jj + 1];
        const int q0 = (int)rintf(a.x * pinv), q1 = (int)rintf(a.y * pinv);
        const int q2 = (int)rintf(a.z * pinv), q3 = (int)rintf(a.w * pinv);
        const int q4 = (int)rintf(c.x * pinv), q5 = (int)rintf(c.y * pinv);
        const int q6 = (int)rintf(c.z * pinv), q7 = (int)rintf(c.w * pinv);
        plo[jj] = (q0 & 0xff) | ((q2 & 0xff) << 8) | ((q4 & 0xff) << 16) | ((q6 & 0xff) << 24);
        phi[jj] = (q1 & 0xff) | ((q3 & 0xff) << 8) | ((q5 & 0xff) << 16) | ((q7 & 0xff) << 24);
        psum += (q0 + q1) + (q2 + q3) + (q4 + q5) + (q6 + q7);
    }
    const int m8psum = -8 * psum;
    const uint M = 0x0F0F0F0Fu;

    float A0 = 0.f, A1 = 0.f;
    int e = start;
    for (; e + 2 <= end; e += 2) {
        const int p0 = flat_papers[e];
        const int p1 = flat_papers[e + 1];
        const uint4 u0 = *reinterpret_cast<const uint4*>(imp_q4 + ((size_t)p0 << 3) + (half << 2));
        const uint4 u1 = *reinterpret_cast<const uint4*>(imp_q4 + ((size_t)p1 << 3) + (half << 2));
        const float s0 = imp_scale[p0];
        const float s1 = imp_scale[p1];
        int d0 = m8psum;
        d0 = __builtin_amdgcn_sdot4((int)(u0.x & M), plo[0], d0, false);
        d0 = __builtin_amdgcn_sdot4((int)((u0.x >> 4) & M), phi[0], d0, false);
        d0 = __builtin_amdgcn_sdot4((int)(u0.y & M), plo[1], d0, false);
        d0 = __builtin_amdgcn_sdot4((int)((u0.y >> 4) & M), phi[1], d0, false);
        d0 = __builtin_amdgcn_sdot4((int)(u0.z & M), plo[2], d0, false);
        d0 = __builtin_amdgcn_sdot4((int)((u0.z >> 4) & M), phi[2], d0, false);
        d0 = __builtin_amdgcn_sdot4((int)(u0.w & M), plo[3], d0, false);
        d0 = __builtin_amdgcn_sdot4((int)((u0.w >> 4) & M), phi[3], d0, false);
        int d1 = m8psum;
        d1 = __builtin_amdgcn_sdot4((int)(u1.x & M), plo[0], d1, false);
        d1 = __builtin_amdgcn_sdot4((int)((u1.x >> 4) & M), phi[0], d1, false);
        d1 = __builtin_amdgcn_sdot4((int)(u1.y & M), plo[1], d1, false);
        d1 = __builtin_amdgcn_sdot4((int)((u1.y >> 4) & M), phi[1], d1, false);
        d1 = __builtin_amdgcn_sdot4((int)(u1.z & M), plo[2], d1, false);
        d1 = __builtin_amdgcn_sdot4((int)((u1.z >> 4) & M), phi[2], d1, false);
        d1 = __builtin_amdgcn_sdot4((int)(u1.w & M), plo[3], d1, false);
        d1 = __builtin_amdgcn_sdot4((int)((u1.w >> 4) & M), phi[3], d1, false);
        A0 = fmaf(s0, (float)d0, A0);
        A1 = fmaf(s1, (float)d1, A1);
    }
    if (e < end) {
        const int p = flat_papers[e];
        const uint4 u = *reinterpret_cast<const uint4*>(imp_q4 + ((size_t)p << 3) + (half << 2));
        const float s = imp_scale[p];
        int d = m8psum;
        d = __builtin_amdgcn_sdot4((int)(u.x & M), plo[0], d, false);
        d = __builtin_amdgcn_sdot4((int)((u.x >> 4) & M), phi[0], d, false);
        d = __builtin_amdgcn_sdot4((int)(u.y & M), plo[1], d, false);
        d = __builtin_amdgcn_sdot4((int)((u.y >> 4) & M), phi[1], d, false);
        d = __builtin_amdgcn_sdot4((int)(u.z & M), plo[2], d, false);
        d = __builtin_amdgcn_sdot4((int)((u.z >> 4) & M), phi[2], d, false);
        d = __builtin_amdgcn_sdot4((int)(u.w & M), plo[3], d, false);
        d = __builtin_amdgcn_sdot4((int)((u.w >> 4) & M), phi[3], d, false);
        A0 = fmaf(s, (float)d, A0);
    }
    const float acc = sp * (A0 + A1);     // per-lane partial over its 32 dims
#else
    // float fallback: value = s*(nib-8)
    float A0 = 0.f, S0 = 0.f;
    float pesum = 0.f;
    #pragma unroll
    for (int k = 0; k < 8; ++k) pesum += pe[k].x + pe[k].y + pe[k].z + pe[k].w;
    for (int e = start; e < end; ++e) {
        const int p = flat_papers[e];
        const uint4 u = *reinterpret_cast<const uint4*>(imp_q4 + ((size_t)p << 3) + (half << 2));
        const float s = imp_scale[p];
        float d = 0.f;
        const uint uu[4] = {u.x, u.y, u.z, u.w};
        #pragma unroll
        for (int jj = 0; jj < 4; ++jj) {
            const uint lo = uu[jj] & 0x0F0F0F0Fu, hi = (uu[jj] >> 4) & 0x0F0F0F0Fu;
            const float4 a = pe[2 * jj], c = pe[2 * jj + 1];
            d += (float)(lo & 0xffu) * a.x + (float)(hi & 0xffu) * a.y
               + (float)((lo >> 8) & 0xffu) * a.z + (float)((hi >> 8) & 0xffu) * a.w
               + (float)((lo >> 16) & 0xffu) * c.x + (float)((hi >> 16) & 0xffu) * c.y
               + (float)(lo >> 24) * c.z + (float)(hi >> 24) * c.w;
        }
        A0 = fmaf(s, d, A0);  S0 += s;
    }
    const float acc = A0 - 8.0f * S0 * pesum;
#endif

    const int n = end - start;
    const float scl = (n > 0) ? rsqrtf((float)n) : 0.0f;
    float v = base + scl * acc;
    v += __shfl_xor(v, 1, 64);            // combine the two halves

    if (half == 0) {
        __builtin_nontemporal_store(v + sb + pb + 3.82f, out + b);
    }
}

// ---------- f32 fallback (ws too small) ----------
__global__ __launch_bounds__(256) void svdpp_main_f32(
    const int*   __restrict__ scientist_ids,
    const int*   __restrict__ paper_ids,
    const int*   __restrict__ flat_papers,
    const int*   __restrict__ row_start,
    const float* __restrict__ scientist_factors,
    const float* __restrict__ paper_factors,
    const float* __restrict__ implicit_factors,
    const float* __restrict__ scientist_bias,
    const float* __restrict__ paper_bias,
    float*       __restrict__ out,
    int B) {
    const int wave = (int)((blockIdx.x * blockDim.x + threadIdx.x) >> 6);
    const int lane = threadIdx.x & 63;
    if (wave >= B) return;
    const int b   = wave;
    const int g   = lane >> 4;
    const int sub = lane & 15;

    const int start = row_start[b];
    const int end   = row_start[b + 1];
    const int n     = end - start;

    float4 accA = make_float4(0.f,0.f,0.f,0.f);
    int i = start;
    for (; i < end; i += 4) {
        const int e = i + g;
        if (e < end) {
            const int p = flat_papers[e];
            const float4 r = *reinterpret_cast<const float4*>(
                implicit_factors + ((size_t)p << 6) + (sub << 2));
            accA.x += r.x; accA.y += r.y; accA.z += r.z; accA.w += r.w;
        }
    }

    const float scale = (n > 0) ? rsqrtf((float)n) : 0.0f;
    const int sid = scientist_ids[b];
    const int pid = paper_ids[b];
    const float4 se = *reinterpret_cast<const float4*>(
        scientist_factors + ((size_t)sid << 6) + (sub << 2));
    const float4 pe = *reinterpret_cast<const float4*>(
        paper_factors + ((size_t)pid << 6) + (sub << 2));

    const float basedot = se.x*pe.x + se.y*pe.y + se.z*pe.z + se.w*pe.w;
    const float tdot    = accA.x*pe.x + accA.y*pe.y + accA.z*pe.z + accA.w*pe.w;
    float v = scale * tdot + ((g == 0) ? basedot : 0.0f);

    #pragma unroll
    for (int off = 1; off < 64; off <<= 1) v += __shfl_xor(v, off, 64);

    if (lane == 0) {
        out[b] = v + scientist_bias[sid] + paper_bias[pid] + 3.82f;
    }
}

extern "C" void kernel_launch(void* const* d_in, const int* in_sizes, int n_in,
                              void* d_out, int out_size, void* d_ws, size_t ws_size,
                              hipStream_t stream) {
    const int* scientist_ids       = (const int*)d_in[0];
    const int* paper_ids           = (const int*)d_in[1];
    const int* flat_papers         = (const int*)d_in[2];
    const int* segment_ids         = (const int*)d_in[3];
    const float* scientist_factors = (const float*)d_in[4];
    const float* paper_factors     = (const float*)d_in[5];
    const float* implicit_factors  = (const float*)d_in[6];
    const float* scientist_bias    = (const float*)d_in[7];
    const float* paper_bias        = (const float*)d_in[8];
    float* out = (float*)d_out;

    const int B      = in_sizes[0];
    const int T      = in_sizes[2];
    const int IMP_N  = in_sizes[6];          // NUM_PAPERS * EMB
    const int NROWS  = IMP_N / EMB;          // NUM_PAPERS

    auto align64 = [](size_t x) { return (x + 63) & ~(size_t)63; };
    size_t off0 = 0;                                   // row_start (B+1 ints)
    size_t off1 = align64(off0 + (size_t)(B + 1) * 4); // imp_q4  (NROWS*32B)
    size_t off2 = align64(off1 + (size_t)NROWS * 32);  // imp_scale (NROWS*4B)
    const size_t need = off2 + (size_t)NROWS * 4;

    int*   row_start  = (int*)((char*)d_ws + off0);
    uint*  imp_q4     = (uint*)((char*)d_ws + off1);
    float* imp_scale  = (float*)((char*)d_ws + off2);

    {
        const int threads = 256;
        const int blocks  = (T + threads - 1) / threads;
        seg_bounds_kernel<<<blocks, threads, 0, stream>>>(segment_ids, row_start, T, B);
    }

    if (ws_size >= need) {
        {
            const int threads = 256;                   // 32 rows per block
            const int blocks  = (NROWS + 31) / 32;
            cvt_q4_kernel<<<blocks, threads, 0, stream>>>(
                implicit_factors, imp_q4, imp_scale, NROWS);
        }
        {
            const int threads = 256;                   // 128 output rows per block
            const int blocks  = (B + 127) / 128;
            svdpp_main_q4<<<blocks, threads, 0, stream>>>(
                scientist_ids, paper_ids, flat_papers, row_start,
                scientist_factors, paper_factors, imp_q4, imp_scale,
                scientist_bias, paper_bias, out, B);
        }
    } else {
        const int threads = 256;
        const int blocks  = (B + 3) / 4;
        svdpp_main_f32<<<blocks, threads, 0, stream>>>(
            scientist_ids, paper_ids, flat_papers, row_start,
            scientist_factors, paper_factors, implicit_factors,
            scientist_bias, paper_bias, out, B);
    }
}

// Round 18
// 104.956 us; speedup vs baseline: 1.3988x; 1.3988x over previous
//
#include <hip/hip_runtime.h>

#define EMB 64
#define CHUNK 256

#if defined(__has_builtin)
#if __has_builtin(__builtin_amdgcn_sdot4)
#define USE_SDOT 1
#endif
#endif
#ifndef USE_SDOT
#define USE_SDOT 0
#endif

// ---------- fused prep: segment boundaries | q4 conversion ----------
__global__ __launch_bounds__(256) void prep_kernel(
    const int* __restrict__ seg, int* __restrict__ row_start, int T, int B,
    const float* __restrict__ src, uint* __restrict__ dst,
    float* __restrict__ scales, int nrows, int segBlocks) {
    if ((int)blockIdx.x < segBlocks) {
        const int t = (int)blockIdx.x * (int)blockDim.x + (int)threadIdx.x;
        if (t >= T) return;
        const int s  = seg[t];
        const int sp = (t == 0) ? -1 : seg[t - 1];
        for (int b = sp + 1; b <= s; ++b) row_start[b] = t;
        if (t == T - 1) {
            for (int b = s + 1; b <= B; ++b) row_start[b] = T;
        }
    } else {
        // f32 -> signed int4 stored excess-8: value = s*q', q' in [-7,7], nib = q'+8
        const int wave = (int)(((size_t)((int)blockIdx.x - segBlocks) * blockDim.x + threadIdx.x) >> 6);
        const int lane = (int)threadIdx.x & 63;
        const int g = lane >> 3, sub = lane & 7;
        const int r = wave * 8 + g;
        if (r >= nrows) return;

        const float* p = src + (size_t)r * EMB + (sub << 3);
        float e[8];
        #pragma unroll
        for (int k = 0; k < 8; ++k) e[k] = p[k];
        float mx = 0.f;
        #pragma unroll
        for (int k = 0; k < 8; ++k) mx = fmaxf(mx, fabsf(e[k]));
        mx = fmaxf(mx, __shfl_xor(mx, 1, 64));
        mx = fmaxf(mx, __shfl_xor(mx, 2, 64));
        mx = fmaxf(mx, __shfl_xor(mx, 4, 64));

        const float scale = mx * (1.0f / 7.0f);
        const float inv   = (mx > 0.f) ? (7.0f / mx) : 0.f;

        uint w = 0;
        #pragma unroll
        for (int k = 0; k < 8; ++k) {
            int q = (int)rintf(e[k] * inv);
            q = q < -7 ? -7 : (q > 7 ? 7 : q);
            w |= ((uint)(q + 8)) << (4 * k);
        }
        dst[(size_t)r * 8 + sub] = w;
        if (sub == 0) scales[r] = scale;
    }
}

// ---------- Kernel B v13: R16 8x8 structure + LDS id staging ----------
// Wave = 8 groups x 8 lanes; group g owns row wave*8+g; lane sub covers dims
// [8*sub..8*sub+7] (one q4 dword). The wave's 8 rows occupy the CONTIGUOUS
// flat range [rs[b0], rs[b0+8]) -> staged into LDS with coalesced loads;
// inner loop reads ids from LDS (group-uniform broadcast, lgkm pipe) so the
// per-entry global id->gather round trip is gone. Chunk loop is wave-uniform.
__global__ __launch_bounds__(256) void svdpp_main_q4(
    const int*   __restrict__ scientist_ids,
    const int*   __restrict__ paper_ids,
    const int*   __restrict__ flat_papers,
    const int*   __restrict__ row_start,
    const float* __restrict__ scientist_factors,
    const float* __restrict__ paper_factors,
    const uint*  __restrict__ imp_q4,
    const float* __restrict__ imp_scale,
    const float* __restrict__ scientist_bias,
    const float* __restrict__ paper_bias,
    float*       __restrict__ out,
    int B) {
    const int wave = (int)((blockIdx.x * blockDim.x + threadIdx.x) >> 6);
    const int lane = threadIdx.x & 63;
    const int g    = lane >> 3;
    const int sub  = lane & 7;
    const int b0   = wave * 8;
    if (b0 >= B) return;
    const bool valid = (b0 + g) < B;
    const int b = valid ? (b0 + g) : (B - 1);
    const int w = (int)(threadIdx.x >> 6);

    __shared__ int lds_ids[4][CHUNK];

    const int sid   = __builtin_nontemporal_load(scientist_ids + b);
    const int pid   = __builtin_nontemporal_load(paper_ids + b);
    const int start = row_start[b];
    const int end   = row_start[b + 1];

    // wave-wide contiguous flat range (shfl at full convergence: safe)
    const int S = __shfl(start, 0, 64);     // row_start[b0]
    const int E = __shfl(end, 63, 64);      // row_start[min(b0+8,B)]

    // paper row (hot table): 2 cached float4 loads
    const float4* pf = reinterpret_cast<const float4*>(
        paper_factors + ((size_t)pid << 6)) + 2 * sub;
    const float4 pe0 = pf[0];
    const float4 pe1 = pf[1];

    // scientist row (zero-reuse): scalar nt loads
    const float* sf = scientist_factors + ((size_t)sid << 6) + (sub << 3);
    float se[8];
    #pragma unroll
    for (int k = 0; k < 8; ++k) se[k] = __builtin_nontemporal_load(sf + k);

    const float sb = __builtin_nontemporal_load(scientist_bias + sid);
    const float pb = __builtin_nontemporal_load(paper_bias + pid);

    const float base = se[0]*pe0.x + se[1]*pe0.y + se[2]*pe0.z + se[3]*pe0.w
                     + se[4]*pe1.x + se[5]*pe1.y + se[6]*pe1.z + se[7]*pe1.w;

#if USE_SDOT
    float pmax = fmaxf(fmaxf(fmaxf(fabsf(pe0.x), fabsf(pe0.y)),
                             fmaxf(fabsf(pe0.z), fabsf(pe0.w))),
                       fmaxf(fmaxf(fabsf(pe1.x), fabsf(pe1.y)),
                             fmaxf(fabsf(pe1.z), fabsf(pe1.w))));
    const float sp   = pmax * (1.0f / 127.0f);
    const float pinv = (pmax > 0.f) ? (127.0f / pmax) : 0.f;
    int qp[8];
    qp[0] = (int)rintf(pe0.x * pinv); qp[1] = (int)rintf(pe0.y * pinv);
    qp[2] = (int)rintf(pe0.z * pinv); qp[3] = (int)rintf(pe0.w * pinv);
    qp[4] = (int)rintf(pe1.x * pinv); qp[5] = (int)rintf(pe1.y * pinv);
    qp[6] = (int)rintf(pe1.z * pinv); qp[7] = (int)rintf(pe1.w * pinv);
    const int plo = (qp[0] & 0xff) | ((qp[2] & 0xff) << 8)
                  | ((qp[4] & 0xff) << 16) | ((qp[6] & 0xff) << 24);
    const int phi = (qp[1] & 0xff) | ((qp[3] & 0xff) << 8)
                  | ((qp[5] & 0xff) << 16) | ((qp[7] & 0xff) << 24);
    const int m8psum = -8 * (qp[0] + qp[1] + qp[2] + qp[3]
                           + qp[4] + qp[5] + qp[6] + qp[7]);
    const uint M = 0x0F0F0F0Fu;

    float A0 = 0.f, A1 = 0.f, A2 = 0.f, A3 = 0.f;
    for (int clo = S; clo < E; clo += CHUNK) {
        const int chi = (clo + CHUNK < E) ? (clo + CHUNK) : E;
        // stage ids: coalesced, wave-uniform loop
        #pragma unroll
        for (int k = 0; k < CHUNK / 64; ++k) {
            const int idx = clo + lane + k * 64;
            if (idx < chi) lds_ids[w][lane + k * 64] = flat_papers[idx];
        }
        // same-wave produce->consume: no barrier needed (compiler waits lgkm)
        int ge = (start > clo) ? start : clo;
        const int gend = (end < chi) ? end : chi;
        for (; ge + 4 <= gend; ge += 4) {
            const int li = ge - clo;
            const int p0 = lds_ids[w][li];
            const int p1 = lds_ids[w][li + 1];
            const int p2 = lds_ids[w][li + 2];
            const int p3 = lds_ids[w][li + 3];
            const uint u0 = imp_q4[((size_t)p0 << 3) + sub];
            const uint u1 = imp_q4[((size_t)p1 << 3) + sub];
            const uint u2 = imp_q4[((size_t)p2 << 3) + sub];
            const uint u3 = imp_q4[((size_t)p3 << 3) + sub];
            const float s0 = imp_scale[p0];
            const float s1 = imp_scale[p1];
            const float s2 = imp_scale[p2];
            const float s3 = imp_scale[p3];
            const int d0 = __builtin_amdgcn_sdot4((int)(u0 & M), plo,
                           __builtin_amdgcn_sdot4((int)((u0 >> 4) & M), phi, m8psum, false), false);
            const int d1 = __builtin_amdgcn_sdot4((int)(u1 & M), plo,
                           __builtin_amdgcn_sdot4((int)((u1 >> 4) & M), phi, m8psum, false), false);
            const int d2 = __builtin_amdgcn_sdot4((int)(u2 & M), plo,
                           __builtin_amdgcn_sdot4((int)((u2 >> 4) & M), phi, m8psum, false), false);
            const int d3 = __builtin_amdgcn_sdot4((int)(u3 & M), plo,
                           __builtin_amdgcn_sdot4((int)((u3 >> 4) & M), phi, m8psum, false), false);
            A0 = fmaf(s0, (float)d0, A0);
            A1 = fmaf(s1, (float)d1, A1);
            A2 = fmaf(s2, (float)d2, A2);
            A3 = fmaf(s3, (float)d3, A3);
        }
        for (; ge < gend; ++ge) {
            const int p = lds_ids[w][ge - clo];
            const uint u = imp_q4[((size_t)p << 3) + sub];
            const float s = imp_scale[p];
            const int d = __builtin_amdgcn_sdot4((int)(u & M), plo,
                          __builtin_amdgcn_sdot4((int)((u >> 4) & M), phi, m8psum, false), false);
            A0 = fmaf(s, (float)d, A0);
        }
    }
    const float acc = sp * ((A0 + A1) + (A2 + A3));
#else
    const float pesum = pe0.x + pe0.y + pe0.z + pe0.w
                      + pe1.x + pe1.y + pe1.z + pe1.w;
    float A0 = 0.f, S0 = 0.f;
    for (int clo = S; clo < E; clo += CHUNK) {
        const int chi = (clo + CHUNK < E) ? (clo + CHUNK) : E;
        #pragma unroll
        for (int k = 0; k < CHUNK / 64; ++k) {
            const int idx = clo + lane + k * 64;
            if (idx < chi) lds_ids[w][lane + k * 64] = flat_papers[idx];
        }
        int ge = (start > clo) ? start : clo;
        const int gend = (end < chi) ? end : chi;
        for (; ge < gend; ++ge) {
            const int p = lds_ids[w][ge - clo];
            const uint u = imp_q4[((size_t)p << 3) + sub];
            const float s = imp_scale[p];
            const uint lo = u & 0x0F0F0F0Fu, hi = (u >> 4) & 0x0F0F0F0Fu;
            const float d = (float)(lo & 0xffu)*pe0.x + (float)(hi & 0xffu)*pe0.y
                          + (float)((lo >> 8) & 0xffu)*pe0.z + (float)((hi >> 8) & 0xffu)*pe0.w
                          + (float)((lo >> 16) & 0xffu)*pe1.x + (float)((hi >> 16) & 0xffu)*pe1.y
                          + (float)(lo >> 24)*pe1.z + (float)(hi >> 24)*pe1.w;
            A0 = fmaf(s, d, A0);  S0 += s;
        }
    }
    const float acc = A0 - 8.0f * S0 * pesum;
#endif

    const int n = end - start;
    const float scale = (n > 0) ? rsqrtf((float)n) : 0.0f;
    float v = base + scale * acc;

    // reduce within the 8-lane group (all lanes reconverged here)
    v += __shfl_xor(v, 1, 64);
    v += __shfl_xor(v, 2, 64);
    v += __shfl_xor(v, 4, 64);

    if (sub == 0 && valid) {
        __builtin_nontemporal_store(v + sb + pb + 3.82f, out + (b0 + g));
    }
}

// ---------- f32 fallback (ws too small) ----------
__global__ __launch_bounds__(256) void svdpp_main_f32(
    const int*   __restrict__ scientist_ids,
    const int*   __restrict__ paper_ids,
    const int*   __restrict__ flat_papers,
    const int*   __restrict__ row_start,
    const float* __restrict__ scientist_factors,
    const float* __restrict__ paper_factors,
    const float* __restrict__ implicit_factors,
    const float* __restrict__ scientist_bias,
    const float* __restrict__ paper_bias,
    float*       __restrict__ out,
    int B) {
    const int wave = (int)((blockIdx.x * blockDim.x + threadIdx.x) >> 6);
    const int lane = threadIdx.x & 63;
    if (wave >= B) return;
    const int b   = wave;
    const int g   = lane >> 4;
    const int sub = lane & 15;

    const int start = row_start[b];
    const int end   = row_start[b + 1];
    const int n     = end - start;

    float4 accA = make_float4(0.f,0.f,0.f,0.f);
    int i = start;
    for (; i < end; i += 4) {
        const int e = i + g;
        if (e < end) {
            const int p = flat_papers[e];
            const float4 r = *reinterpret_cast<const float4*>(
                implicit_factors + ((size_t)p << 6) + (sub << 2));
            accA.x += r.x; accA.y += r.y; accA.z += r.z; accA.w += r.w;
        }
    }

    const float scale = (n > 0) ? rsqrtf((float)n) : 0.0f;
    const int sid = scientist_ids[b];
    const int pid = paper_ids[b];
    const float4 se = *reinterpret_cast<const float4*>(
        scientist_factors + ((size_t)sid << 6) + (sub << 2));
    const float4 pe = *reinterpret_cast<const float4*>(
        paper_factors + ((size_t)pid << 6) + (sub << 2));

    const float basedot = se.x*pe.x + se.y*pe.y + se.z*pe.z + se.w*pe.w;
    const float tdot    = accA.x*pe.x + accA.y*pe.y + accA.z*pe.z + accA.w*pe.w;
    float v = scale * tdot + ((g == 0) ? basedot : 0.0f);

    #pragma unroll
    for (int off = 1; off < 64; off <<= 1) v += __shfl_xor(v, off, 64);

    if (lane == 0) {
        out[b] = v + scientist_bias[sid] + paper_bias[pid] + 3.82f;
    }
}

extern "C" void kernel_launch(void* const* d_in, const int* in_sizes, int n_in,
                              void* d_out, int out_size, void* d_ws, size_t ws_size,
                              hipStream_t stream) {
    const int* scientist_ids       = (const int*)d_in[0];
    const int* paper_ids           = (const int*)d_in[1];
    const int* flat_papers         = (const int*)d_in[2];
    const int* segment_ids         = (const int*)d_in[3];
    const float* scientist_factors = (const float*)d_in[4];
    const float* paper_factors     = (const float*)d_in[5];
    const float* implicit_factors  = (const float*)d_in[6];
    const float* scientist_bias    = (const float*)d_in[7];
    const float* paper_bias        = (const float*)d_in[8];
    float* out = (float*)d_out;

    const int B      = in_sizes[0];
    const int T      = in_sizes[2];
    const int IMP_N  = in_sizes[6];          // NUM_PAPERS * EMB
    const int NROWS  = IMP_N / EMB;          // NUM_PAPERS

    auto align64 = [](size_t x) { return (x + 63) & ~(size_t)63; };
    size_t off0 = 0;                                   // row_start (B+1 ints)
    size_t off1 = align64(off0 + (size_t)(B + 1) * 4); // imp_q4  (NROWS*32B)
    size_t off2 = align64(off1 + (size_t)NROWS * 32);  // imp_scale (NROWS*4B)
    const size_t need = off2 + (size_t)NROWS * 4;

    int*   row_start  = (int*)((char*)d_ws + off0);
    uint*  imp_q4     = (uint*)((char*)d_ws + off1);
    float* imp_scale  = (float*)((char*)d_ws + off2);

    if (ws_size >= need) {
        {
            const int threads   = 256;
            const int segBlocks = (T + threads - 1) / threads;
            const int cvtBlocks = (NROWS + 31) / 32;   // 8 rows per wave
            prep_kernel<<<segBlocks + cvtBlocks, threads, 0, stream>>>(
                segment_ids, row_start, T, B,
                implicit_factors, imp_q4, imp_scale, NROWS, segBlocks);
        }
        {
            const int threads = 256;                   // 32 output rows per block
            const int blocks  = (B + 31) / 32;
            svdpp_main_q4<<<blocks, threads, 0, stream>>>(
                scientist_ids, paper_ids, flat_papers, row_start,
                scientist_factors, paper_factors, imp_q4, imp_scale,
                scientist_bias, paper_bias, out, B);
        }
    } else {
        {
            const int threads = 256;
            const int blocks  = (T + threads - 1) / threads;
            // seg bounds only (prep without cvt): reuse prep with segBlocks=blocks
            prep_kernel<<<blocks, threads, 0, stream>>>(
                segment_ids, row_start, T, B,
                implicit_factors, (uint*)nullptr, (float*)nullptr, 0, blocks);
        }
        const int threads = 256;
        const int blocks  = (B + 3) / 4;
        svdpp_main_f32<<<blocks, threads, 0, stream>>>(
            scientist_ids, paper_ids, flat_papers, row_start,
            scientist_factors, paper_factors, implicit_factors,
            scientist_bias, paper_bias, out, B);
    }
}